// Round 11
// baseline (173.228 us; speedup 1.0000x reference)
//
#include <hip/hip_runtime.h>
#include <hip/hip_bf16.h>

#define NVV 50
#define C1 64
#define C2 128
#define HW1 64
#define HW2 32

typedef short bf16x8 __attribute__((ext_vector_type(8)));
typedef short s16x4 __attribute__((ext_vector_type(4)));
typedef float f32x4 __attribute__((ext_vector_type(4)));
typedef int i32x4 __attribute__((ext_vector_type(4)));

__device__ inline short f2bf(float x) {
    unsigned u = __builtin_bit_cast(unsigned, x);
    unsigned r = (u + 0x7FFFu + ((u >> 16) & 1u)) >> 16;
    return (short)r;
}
__device__ inline float bf2f(short x) {
    unsigned u = ((unsigned)(unsigned short)x) << 16;
    return __builtin_bit_cast(float, u);
}

// ---------------- kernel 1: conv1 (blocks 0..895) + weight packing (blocks 896..3523) ----------------
// conv1 builds its own w1 A-frags from LDS (no WPK1 dependency); pack path also zeroes CNT.
__global__ __launch_bounds__(256) void conv1_pack(const float* __restrict__ img,
                                                  const float* __restrict__ w1,
                                                  const float* __restrict__ b1,
                                                  const float* __restrict__ w2,
                                                  const float* __restrict__ w3,
                                                  const float* __restrict__ mw1, const float* __restrict__ mb1,
                                                  const float* __restrict__ mw2, const float* __restrict__ mw3,
                                                  __hip_bfloat16* __restrict__ A1c,
                                                  __hip_bfloat16* __restrict__ WPK2,
                                                  __hip_bfloat16* __restrict__ WPK3,
                                                  __hip_bfloat16* __restrict__ WPM1,
                                                  __hip_bfloat16* __restrict__ WPM2,
                                                  __hip_bfloat16* __restrict__ WPM3,
                                                  int* __restrict__ CNT) {
    __shared__ float tile[3 * 9 * 132];
    __shared__ float w1s[1728];
    int b = blockIdx.x;
    int tid = threadIdx.x;

    if (b >= 896) {
        // ---------- pack path ----------
        int i = (b - 896) * 256 + tid;
        if (i < 16) CNT[i] = 0;
        if (i < 2048) {
            // (WPK1 slot retired — conv1 self-packs w1)
        } else if (i < 75776) {
            int q = i - 2048;
            int j = q & 7, l = (q >> 3) & 63;
            int rest = q >> 9;
            int mtile = rest & 7;
            rest >>= 3;
            int icb = rest & 1;
            int kk = rest >> 1;
            int oc = mtile * 16 + (l & 15);
            int ic = icb * 32 + (l >> 4) * 8 + j;
            int ky = kk / 3, kx = kk % 3;
            WPK2[q] = __float2bfloat16(w2[((oc * 64 + ic) * 3 + ky) * 3 + kx]);
        } else if (i < 665600) {
            int q = i - 75776;
            int j = q & 7, l = (q >> 3) & 63;
            int rest = q >> 9;
            int m = rest & 31;
            rest >>= 5;
            int icb = rest & 3;
            int kk = rest >> 2;
            int oc = m * 16 + (l & 15);
            int ic = icb * 32 + (l >> 4) * 8 + j;
            int ky = kk / 3, kx = kk % 3;
            WPK3[q] = __float2bfloat16(w3[((oc * 128 + ic) * 3 + ky) * 3 + kx]);
        } else if (i < 672768) {
            int q = i - 665600;
            if (q < 2048) {
                int j = q & 7, l = (q >> 3) & 63, mf = q >> 9;
                int nn = mf * 16 + (l & 15);
                int ch = (l >> 4) * 8 + j;
                float v = ch < 16 ? mw1[ch * 64 + nn] : (ch == 16 ? mb1[nn] : 0.f);
                WPM1[q] = __float2bfloat16(v);
            } else if (q < 6144) {
                int p = q - 2048;
                int j = p & 7, l = (p >> 3) & 63, f = p >> 9;
                int kb = f >> 2, mf = f & 3;
                int nn = mf * 16 + (l & 15);
                int k = kb * 32 + (l >> 4) * 8 + j;
                WPM2[p] = __float2bfloat16(mw2[k * 64 + nn]);
            } else {
                int p = q - 6144;
                int j = p & 7, l = (p >> 3) & 63, kb = p >> 9;
                int m = l & 15;
                int k = kb * 32 + (l >> 4) * 8 + j;
                WPM3[p] = __float2bfloat16(m < 4 ? mw3[k * 4 + m] : 0.f);
            }
        }
        return;
    }

    // ---------- conv1 path (XCD-locality grid) ----------
    int xcd = b & 7, slot = b >> 3;
    int v = xcd + 8 * (slot >> 4);
    int oyb = slot & 15;
    if (v >= NVV) return;
    const float* ip = img + (size_t)v * 3 * 128 * 128;
    int iy0 = oyb * 8;
    for (int idx = tid; idx < 3456; idx += 256) {
        int ix = idx & 127;
        int t = idx >> 7;
        int iyl = t % 9, ic = t / 9;
        int iy = iy0 + iyl;
        tile[(ic * 9 + iyl) * 132 + ix] = (iy < 128) ? ip[(ic * 128 + iy) * 128 + ix] : 0.f;
    }
    if (tid < 108) {
        int c = tid & 3;
        int t = tid >> 2;
        int iyl = t % 9, ic = t / 9;
        tile[(ic * 9 + iyl) * 132 + 128 + c] = 0.f;
    }
    for (int i = tid; i < 1728; i += 256) w1s[i] = w1[i];
    __syncthreads();

    int l = tid & 63, w = tid >> 6;
    int lane16 = l & 15, lgrp = l >> 4;
    int oy = oyb * 4 + w;

    int offj[8];
    bool okj[8];
    #pragma unroll
    for (int j = 0; j < 8; ++j) {
        int k = lgrp * 8 + j;
        bool ok = k < 27;
        int kc = ok ? k : 0;
        int ic = kc / 9, r = kc % 9;
        int ky = r / 3, kx = r % 3;
        offj[j] = (ic * 9 + 2 * w + ky) * 132 + kx;
        okj[j] = ok;
    }

    bf16x8 a[4];
    #pragma unroll
    for (int mf = 0; mf < 4; ++mf) {
        #pragma unroll
        for (int j = 0; j < 8; ++j) {
            int k = lgrp * 8 + j;
            a[mf][j] = (k < 27) ? f2bf(w1s[(mf * 16 + lane16) * 27 + k]) : (short)0;
        }
    }

    f32x4 acc[4][4];
    #pragma unroll
    for (int mf = 0; mf < 4; ++mf)
        #pragma unroll
        for (int nf = 0; nf < 4; ++nf)
            acc[mf][nf] = (f32x4){0.f, 0.f, 0.f, 0.f};

    #pragma unroll
    for (int nf = 0; nf < 4; ++nf) {
        int ox = nf * 16 + lane16;
        bf16x8 bb;
        #pragma unroll
        for (int j = 0; j < 8; ++j) {
            float x = tile[offj[j] + 2 * ox];
            bb[j] = okj[j] ? f2bf(x) : (short)0;
        }
        #pragma unroll
        for (int mf = 0; mf < 4; ++mf)
            acc[mf][nf] = __builtin_amdgcn_mfma_f32_16x16x32_bf16(a[mf], bb, acc[mf][nf], 0, 0, 0);
    }

    #pragma unroll
    for (int mf = 0; mf < 4; ++mf) {
        #pragma unroll
        for (int nf = 0; nf < 4; ++nf) {
            int px = (v * 64 + oy) * 64 + nf * 16 + lane16;
            s16x4 sv;
            #pragma unroll
            for (int r = 0; r < 4; ++r) {
                int oc = mf * 16 + lgrp * 4 + r;
                sv[r] = f2bf(fmaxf(acc[mf][nf][r] + b1[oc], 0.f));
            }
            *(s16x4*)((short*)A1c + (size_t)px * 64 + mf * 16 + lgrp * 4) = sv;
        }
    }
}

// ---------------- kernel 2: conv2 + per-region mean finisher (last-block pattern) ----------------
__global__ __launch_bounds__(128) void conv2_mean(const __hip_bfloat16* __restrict__ A1c,
                                                  const __hip_bfloat16* __restrict__ wpack,
                                                  const float* __restrict__ b2,
                                                  __hip_bfloat16* __restrict__ A2c,
                                                  __hip_bfloat16* __restrict__ XBc,
                                                  int* __restrict__ CNT) {
    __shared__ int isLast;
    int b = blockIdx.x;
    int xcd = b & 7, slot = b >> 3;
    int v = xcd + 8 * (slot >> 4);
    int oyb = slot & 15;                  // 16 row-pair regions
    if (v >= NVV) return;
    int tid = threadIdx.x;
    int l = tid & 63;
    int wm = tid >> 6;                    // 0..1 over oc halves
    int lane16 = l & 15, lgrp = l >> 4;

    int oxv[4], oyv[4];
    const short* pxb[4];
    bool rOOB[4], cOOB[4];
    const short* ibase = (const short*)A1c + (size_t)v * 64 * 64 * 64;
    #pragma unroll
    for (int nf = 0; nf < 4; ++nf) {
        int px = nf * 16 + lane16;        // 0..63
        int dy = px >> 5, ox = px & 31;
        oxv[nf] = ox;
        oyv[nf] = oyb * 2 + dy;
        pxb[nf] = ibase + ((size_t)(2 * oyv[nf]) * 64 + 2 * ox) * 64 + lgrp * 8;
        rOOB[nf] = (oyv[nf] == 31);
        cOOB[nf] = (ox == 31);
    }

    f32x4 acc[4][4];
    #pragma unroll
    for (int mf = 0; mf < 4; ++mf)
        #pragma unroll
        for (int nf = 0; nf < 4; ++nf)
            acc[mf][nf] = (f32x4){0.f, 0.f, 0.f, 0.f};

    const short* ab = (const short*)wpack + wm * 4 * 512 + l * 8;
    const bf16x8 bz = (bf16x8){0, 0, 0, 0, 0, 0, 0, 0};

    #pragma unroll
    for (int kk = 0; kk < 9; ++kk) {
        const int ky = kk / 3, kx = kk % 3;
        #pragma unroll
        for (int icb = 0; icb < 2; ++icb) {
            bf16x8 a[4];
            #pragma unroll
            for (int mf = 0; mf < 4; ++mf)
                a[mf] = *(const bf16x8*)(ab + ((kk * 2 + icb) * 8 + mf) * 512);

            bf16x8 bb[4];
            #pragma unroll
            for (int nf = 0; nf < 4; ++nf) {
                bf16x8 t = *(const bf16x8*)(pxb[nf] + (ky * 64 + kx) * 64 + icb * 32);
                bool dead = (ky == 2 && rOOB[nf]) || (kx == 2 && cOOB[nf]);
                bb[nf] = dead ? bz : t;
            }
            #pragma unroll
            for (int mf = 0; mf < 4; ++mf)
                #pragma unroll
                for (int nf = 0; nf < 4; ++nf)
                    acc[mf][nf] = __builtin_amdgcn_mfma_f32_16x16x32_bf16(a[mf], bb[nf], acc[mf][nf], 0, 0, 0);
        }
    }

    #pragma unroll
    for (int nf = 0; nf < 4; ++nf) {
        int pix = oyv[nf] * 32 + oxv[nf];
        short* ob = (short*)A2c + ((size_t)v * 1024 + pix) * 128 + wm * 64;
        #pragma unroll
        for (int mf = 0; mf < 4; ++mf) {
            f32x4 bv = *(const f32x4*)(b2 + wm * 64 + mf * 16 + lgrp * 4);
            s16x4 sv;
            #pragma unroll
            for (int r = 0; r < 4; ++r) sv[r] = f2bf(fmaxf(acc[mf][nf][r] + bv[r], 0.f));
            *(s16x4*)(ob + mf * 16 + lgrp * 4) = sv;
        }
    }

    // ----- last-block-per-region mean: XBc[region oyb] = mean_v A2c -----
    __threadfence();
    if (tid == 0) {
        int old = atomicAdd(&CNT[oyb], 1);
        isLast = (old == NVV - 1) ? 1 : 0;
    }
    __syncthreads();
    if (isLast) {
        __threadfence();
        for (int it = tid; it < 1024; it += 128) {       // 64 px * 16 groups
            int pp = oyb * 64 + (it >> 4);
            int g = it & 15;
            float accm[8] = {0.f, 0.f, 0.f, 0.f, 0.f, 0.f, 0.f, 0.f};
            for (int vv = 0; vv < NVV; ++vv) {
                bf16x8 x = *(const bf16x8*)((const short*)A2c + ((size_t)vv * 1024 + pp) * 128 + g * 8);
                #pragma unroll
                for (int j = 0; j < 8; ++j) accm[j] += bf2f(x[j]);
            }
            bf16x8 o;
            #pragma unroll
            for (int j = 0; j < 8; ++j) o[j] = f2bf(accm[j] * (1.0f / NVV));
            *(bf16x8*)((short*)XBc + (size_t)pp * 128 + g * 8) = o;
        }
    }
}

// ---------------- conv3 implicit GEMM (fully unrolled K): grid (8 oc-tiles, 32 px-tiles), 2 waves ----------------
__global__ __launch_bounds__(128) void conv3_mfma(const __hip_bfloat16* __restrict__ XBc,
                                                  const __hip_bfloat16* __restrict__ wpack,
                                                  const float* __restrict__ b3,
                                                  __hip_bfloat16* __restrict__ VOLc) {
    int tid = threadIdx.x;
    int l = tid & 63;
    int wn = tid >> 6;
    int lane16 = l & 15, lgrp = l >> 4;

    int px = blockIdx.y * 32 + wn * 16 + lane16;
    int y = px >> 5, x = px & 31;

    const short* pxb = (const short*)XBc + ((ptrdiff_t)(y - 1) * 32 + (x - 1)) * 128 + lgrp * 8;
    bool tOOB = (y == 0), bOOB = (y == 31), lOOB = (x == 0), rOOB = (x == 31);

    f32x4 acc[4];
    #pragma unroll
    for (int mf = 0; mf < 4; ++mf) acc[mf] = (f32x4){0.f, 0.f, 0.f, 0.f};

    const short* ab = (const short*)wpack + (size_t)blockIdx.x * 4 * 512 + l * 8;
    const bf16x8 bzv = (bf16x8){0, 0, 0, 0, 0, 0, 0, 0};

    #pragma unroll
    for (int kk = 0; kk < 9; ++kk) {
        const int ky = kk / 3, kx = kk % 3;
        bool dead = (ky == 0 && tOOB) || (ky == 2 && bOOB) || (kx == 0 && lOOB) || (kx == 2 && rOOB);
        #pragma unroll
        for (int icb = 0; icb < 4; ++icb) {
            bf16x8 t = *(const bf16x8*)(pxb + (ky * 32 + kx) * 128 + icb * 32);
            bf16x8 bb = dead ? bzv : t;
            #pragma unroll
            for (int mf = 0; mf < 4; ++mf) {
                bf16x8 a = *(const bf16x8*)(ab + (size_t)((kk * 4 + icb) * 32 + mf) * 512);
                acc[mf] = __builtin_amdgcn_mfma_f32_16x16x32_bf16(a, bb, acc[mf], 0, 0, 0);
            }
        }
    }

    int oc_base = blockIdx.x * 64;
    #pragma unroll
    for (int mf = 0; mf < 4; ++mf) {
        f32x4 bv = *(const f32x4*)(b3 + oc_base + mf * 16 + lgrp * 4);
        #pragma unroll
        for (int r = 0; r < 4; ++r) {
            int oc = oc_base + mf * 16 + lgrp * 4 + r;
            int c = oc >> 5, iz = oc & 31;
            VOLc[((size_t)((iz * 32 + y) * 32 + x)) * 16 + c] = __float2bfloat16(acc[mf][r] + bv[r]);
        }
    }
}

// ---------------- fused trilinear + MLP + volume render: wave = 1 pixel x 64 samples ----------------
__global__ __launch_bounds__(256) void mlp_render(const __hip_bfloat16* __restrict__ VOLc,
                                                  const float* __restrict__ rays,
                                                  const __hip_bfloat16* __restrict__ wpm1,
                                                  const __hip_bfloat16* __restrict__ wpm2,
                                                  const __hip_bfloat16* __restrict__ wpm3,
                                                  const float* __restrict__ mb2,
                                                  const float* __restrict__ mb3,
                                                  float* __restrict__ out) {
    __shared__ short hbuf[4][32 * 72];
    __shared__ f32x4 rawb[4][64];
    int tid = threadIdx.x;
    int w = tid >> 6, l = tid & 63;
    int lane16 = l & 15, lgrp = l >> 4;
    short* hb = hbuf[w];
    int pix = blockIdx.x * 4 + w;          // wave-uniform pixel

    bf16x8 a1[4];
    #pragma unroll
    for (int mf = 0; mf < 4; ++mf)
        a1[mf] = *(const bf16x8*)((const short*)wpm1 + (mf * 64 + l) * 8);
    bf16x8 a2[2][4];
    #pragma unroll
    for (int kb = 0; kb < 2; ++kb)
        #pragma unroll
        for (int mf = 0; mf < 4; ++mf)
            a2[kb][mf] = *(const bf16x8*)((const short*)wpm2 + ((kb * 4 + mf) * 64 + l) * 8);
    bf16x8 a3[2];
    a3[0] = *(const bf16x8*)((const short*)wpm3 + (0 * 64 + l) * 8);
    a3[1] = *(const bf16x8*)((const short*)wpm3 + (1 * 64 + l) * 8);
    f32x4 b3v = *(const f32x4*)(mb3);

    const bf16x8 bz = (bf16x8){0, 0, 0, 0, 0, 0, 0, 0};
    const bf16x8 bbias = (bf16x8){(short)0x3F80, 0, 0, 0, 0, 0, 0, 0};

    float o0 = rays[pix], o1 = rays[4096 + pix], o2 = rays[2 * 4096 + pix];
    float d0 = rays[3 * 4096 + pix], d1 = rays[4 * 4096 + pix], d2 = rays[5 * 4096 + pix];
    float nearv = rays[6 * 4096 + pix], farv = rays[7 * 4096 + pix];

    int nfg = l >> 5, hf = (l >> 4) & 1;

    for (int rep = 0; rep < 2; ++rep) {
        int s = rep * 32 + nfg * 16 + lane16;
        float t = (float)s / 63.0f;
        float z = nearv + (farv - nearv) * t;
        float px = o0 + d0 * z, py = o1 + d1 * z, pz = o2 + d2 * z;
        float cx = fminf(fmaxf((px + 1.f) * 15.5f, 0.f), 31.f);
        float cy = fminf(fmaxf((py + 1.f) * 15.5f, 0.f), 31.f);
        float cz = fminf(fmaxf((pz + 1.f) * 15.5f, 0.f), 31.f);
        int ix = min((int)floorf(cx), 30);
        int iy = min((int)floorf(cy), 30);
        int iz = min((int)floorf(cz), 30);
        float fx = cx - (float)ix, fy = cy - (float)iy, fz = cz - (float)iz;
        float gx = 1.f - fx, gy = 1.f - fy, gz = 1.f - fz;
        float wv[8] = {gz * gy * gx, gz * gy * fx, gz * fy * gx, gz * fy * fx,
                       fz * gy * gx, fz * gy * fx, fz * fy * gx, fz * fy * fx};
        const int co[8] = {0, 16, 512, 528, 16384, 16400, 16896, 16912};
        int base = (iz * 32 + iy) * 32 + ix;
        const short* vp = (const short*)VOLc + (size_t)base * 16 + hf * 8;

        float f8[8] = {0.f, 0.f, 0.f, 0.f, 0.f, 0.f, 0.f, 0.f};
        #pragma unroll
        for (int c = 0; c < 8; ++c) {
            bf16x8 cv = *(const bf16x8*)(vp + co[c]);
            #pragma unroll
            for (int j = 0; j < 8; ++j) f8[j] += wv[c] * bf2f(cv[j]);
        }
        bf16x8 own;
        #pragma unroll
        for (int j = 0; j < 8; ++j) own[j] = f2bf(f8[j]);

        i32x4 oi = __builtin_bit_cast(i32x4, own);
        i32x4 si;
        si[0] = __shfl_xor(oi[0], 32);
        si[1] = __shfl_xor(oi[1], 32);
        si[2] = __shfl_xor(oi[2], 32);
        si[3] = __shfl_xor(oi[3], 32);
        bf16x8 swf = __builtin_bit_cast(bf16x8, si);

        bf16x8 b0 = (lgrp < 2) ? own : ((lgrp == 2) ? bbias : bz);
        bf16x8 b1 = (lgrp < 2) ? swf : ((lgrp == 2) ? bbias : bz);

        f32x4 acc1[4][2];
        #pragma unroll
        for (int mf = 0; mf < 4; ++mf) {
            acc1[mf][0] = (f32x4){0.f, 0.f, 0.f, 0.f};
            acc1[mf][1] = (f32x4){0.f, 0.f, 0.f, 0.f};
            acc1[mf][0] = __builtin_amdgcn_mfma_f32_16x16x32_bf16(a1[mf], b0, acc1[mf][0], 0, 0, 0);
            acc1[mf][1] = __builtin_amdgcn_mfma_f32_16x16x32_bf16(a1[mf], b1, acc1[mf][1], 0, 0, 0);
        }
        #pragma unroll
        for (int mf = 0; mf < 4; ++mf) {
            #pragma unroll
            for (int nf = 0; nf < 2; ++nf) {
                s16x4 sv;
                #pragma unroll
                for (int r = 0; r < 4; ++r) sv[r] = f2bf(fmaxf(acc1[mf][nf][r], 0.f));
                *(s16x4*)(hb + (nf * 16 + lane16) * 72 + mf * 16 + lgrp * 4) = sv;
            }
        }

        f32x4 acc2[4][2];
        #pragma unroll
        for (int mf = 0; mf < 4; ++mf) {
            acc2[mf][0] = (f32x4){0.f, 0.f, 0.f, 0.f};
            acc2[mf][1] = (f32x4){0.f, 0.f, 0.f, 0.f};
        }
        #pragma unroll
        for (int nf = 0; nf < 2; ++nf) {
            #pragma unroll
            for (int kb = 0; kb < 2; ++kb) {
                bf16x8 bh = *(const bf16x8*)(hb + (nf * 16 + lane16) * 72 + kb * 32 + lgrp * 8);
                #pragma unroll
                for (int mf = 0; mf < 4; ++mf)
                    acc2[mf][nf] = __builtin_amdgcn_mfma_f32_16x16x32_bf16(a2[kb][mf], bh, acc2[mf][nf], 0, 0, 0);
            }
        }
        #pragma unroll
        for (int mf = 0; mf < 4; ++mf) {
            f32x4 bv = *(const f32x4*)(mb2 + mf * 16 + lgrp * 4);
            #pragma unroll
            for (int nf = 0; nf < 2; ++nf) {
                s16x4 sv;
                #pragma unroll
                for (int r = 0; r < 4; ++r) sv[r] = f2bf(fmaxf(acc2[mf][nf][r] + bv[r], 0.f));
                *(s16x4*)(hb + (nf * 16 + lane16) * 72 + mf * 16 + lgrp * 4) = sv;
            }
        }

        f32x4 acc3[2];
        acc3[0] = (f32x4){0.f, 0.f, 0.f, 0.f};
        acc3[1] = (f32x4){0.f, 0.f, 0.f, 0.f};
        #pragma unroll
        for (int nf = 0; nf < 2; ++nf) {
            #pragma unroll
            for (int kb = 0; kb < 2; ++kb) {
                bf16x8 bh = *(const bf16x8*)(hb + (nf * 16 + lane16) * 72 + kb * 32 + lgrp * 8);
                acc3[nf] = __builtin_amdgcn_mfma_f32_16x16x32_bf16(a3[kb], bh, acc3[nf], 0, 0, 0);
            }
        }
        if (lgrp == 0) {
            #pragma unroll
            for (int nf = 0; nf < 2; ++nf)
                rawb[w][rep * 32 + nf * 16 + lane16] = acc3[nf] + b3v;
        }
    }

    // ---- wave-parallel volume rendering ----
    f32x4 rv = rawb[w][l];
    float dz = (farv - nearv) * (1.f / 63.f);
    float zl = nearv + (farv - nearv) * ((float)l / 63.0f);
    float delta = (l == 63) ? 1e10f : dz;
    float sigma = fmaxf(rv[3], 0.f);
    float alpha = 1.f - __expf(-sigma * delta);
    float la = __builtin_log2f(1.f - alpha + 1e-10f);

    float inc = la;
    #pragma unroll
    for (int off = 1; off < 64; off <<= 1) {
        float y = __shfl_up(inc, off);
        if (l >= off) inc += y;
    }
    float T = __builtin_exp2f(inc - la);
    float wt = alpha * T;

    float cr = wt / (1.f + __expf(-rv[0]));
    float cg = wt / (1.f + __expf(-rv[1]));
    float cb = wt / (1.f + __expf(-rv[2]));
    float cd = wt * zl;

    #pragma unroll
    for (int off = 32; off > 0; off >>= 1) {
        cr += __shfl_down(cr, off);
        cg += __shfl_down(cg, off);
        cb += __shfl_down(cb, off);
        cd += __shfl_down(cd, off);
    }
    if (l == 0) {
        out[pix]             = cr;
        out[4096 + pix]      = cg;
        out[2 * 4096 + pix]  = cb;
        out[12288 + pix]     = cd;
    }
}

extern "C" void kernel_launch(void* const* d_in, const int* in_sizes, int n_in,
                              void* d_out, int out_size, void* d_ws, size_t ws_size,
                              hipStream_t stream) {
    const float* images = (const float*)d_in[0];
    const float* rays   = (const float*)d_in[1];
    const float* w1 = (const float*)d_in[2];
    const float* b1 = (const float*)d_in[3];
    const float* w2 = (const float*)d_in[4];
    const float* b2 = (const float*)d_in[5];
    const float* w3 = (const float*)d_in[6];
    const float* b3 = (const float*)d_in[7];
    const float* mw1 = (const float*)d_in[8];
    const float* mb1 = (const float*)d_in[9];
    const float* mw2 = (const float*)d_in[10];
    const float* mb2 = (const float*)d_in[11];
    const float* mw3 = (const float*)d_in[12];
    const float* mb3 = (const float*)d_in[13];
    float* out = (float*)d_out;

    // workspace layout (bf16 region, then counters)
    __hip_bfloat16* A1c  = (__hip_bfloat16*)d_ws;              // 13107200 bf16
    __hip_bfloat16* WPK2 = A1c + 13107200;                     // 73728
    __hip_bfloat16* WPK1 = WPK2 + 73728;                       // 2048 (retired, kept for layout)
    __hip_bfloat16* VOLc = WPK1 + 2048;                        // 524288
    __hip_bfloat16* WPM1 = VOLc + 524288;                      // 2048
    __hip_bfloat16* WPM2 = WPM1 + 2048;                        // 4096
    __hip_bfloat16* WPM3 = WPM2 + 4096;                        // 1024
    __hip_bfloat16* A2c  = WPM3 + 1024;                        // 6553600
    __hip_bfloat16* XBc  = A2c + 6553600;                      // 131072
    __hip_bfloat16* WPK3 = XBc + 131072;                       // 589824
    int* CNT             = (int*)(WPK3 + 589824);              // 16 ints

    conv1_pack<<<dim3(3524), dim3(256), 0, stream>>>(images, w1, b1, w2, w3, mw1, mb1, mw2, mw3,
                                                     A1c, WPK2, WPK3, WPM1, WPM2, WPM3, CNT);
    conv2_mean<<<dim3(896), dim3(128), 0, stream>>>(A1c, WPK2, b2, A2c, XBc, CNT);
    conv3_mfma<<<dim3(8, 32), dim3(128), 0, stream>>>(XBc, WPK3, b3, VOLc);
    mlp_render<<<dim3(1024), dim3(256), 0, stream>>>(VOLc, rays, WPM1, WPM2, WPM3, mb2, mb3, out);
}

// Round 12
// 83.287 us; speedup vs baseline: 2.0799x; 2.0799x over previous
//
#include <hip/hip_runtime.h>
#include <hip/hip_bf16.h>

#define NVV 50
#define C1 64
#define C2 128
#define HW1 64
#define HW2 32

typedef short bf16x8 __attribute__((ext_vector_type(8)));
typedef short s16x4 __attribute__((ext_vector_type(4)));
typedef float f32x4 __attribute__((ext_vector_type(4)));
typedef int i32x4 __attribute__((ext_vector_type(4)));

__device__ inline short f2bf(float x) {
    unsigned u = __builtin_bit_cast(unsigned, x);
    unsigned r = (u + 0x7FFFu + ((u >> 16) & 1u)) >> 16;
    return (short)r;
}
__device__ inline float bf2f(short x) {
    unsigned u = ((unsigned)(unsigned short)x) << 16;
    return __builtin_bit_cast(float, u);
}

// ---------------- kernel 1: conv1 (blocks 0..895) + weight packing (blocks 896..3523) ----------------
// conv1 builds its own w1 A-frags from LDS (no WPK1 dependency).
__global__ __launch_bounds__(256) void conv1_pack(const float* __restrict__ img,
                                                  const float* __restrict__ w1,
                                                  const float* __restrict__ b1,
                                                  const float* __restrict__ w2,
                                                  const float* __restrict__ w3,
                                                  const float* __restrict__ mw1, const float* __restrict__ mb1,
                                                  const float* __restrict__ mw2, const float* __restrict__ mw3,
                                                  __hip_bfloat16* __restrict__ A1c,
                                                  __hip_bfloat16* __restrict__ WPK2,
                                                  __hip_bfloat16* __restrict__ WPK3,
                                                  __hip_bfloat16* __restrict__ WPM1,
                                                  __hip_bfloat16* __restrict__ WPM2,
                                                  __hip_bfloat16* __restrict__ WPM3) {
    __shared__ float tile[3 * 9 * 132];
    __shared__ float w1s[1728];
    int b = blockIdx.x;
    int tid = threadIdx.x;

    if (b >= 896) {
        // ---------- pack path ----------
        int i = (b - 896) * 256 + tid;
        if (i < 2048) {
            // (WPK1 slot retired — conv1 self-packs w1)
        } else if (i < 75776) {
            int q = i - 2048;
            int j = q & 7, l = (q >> 3) & 63;
            int rest = q >> 9;
            int mtile = rest & 7;
            rest >>= 3;
            int icb = rest & 1;
            int kk = rest >> 1;
            int oc = mtile * 16 + (l & 15);
            int ic = icb * 32 + (l >> 4) * 8 + j;
            int ky = kk / 3, kx = kk % 3;
            WPK2[q] = __float2bfloat16(w2[((oc * 64 + ic) * 3 + ky) * 3 + kx]);
        } else if (i < 665600) {
            int q = i - 75776;
            int j = q & 7, l = (q >> 3) & 63;
            int rest = q >> 9;
            int m = rest & 31;
            rest >>= 5;
            int icb = rest & 3;
            int kk = rest >> 2;
            int oc = m * 16 + (l & 15);
            int ic = icb * 32 + (l >> 4) * 8 + j;
            int ky = kk / 3, kx = kk % 3;
            WPK3[q] = __float2bfloat16(w3[((oc * 128 + ic) * 3 + ky) * 3 + kx]);
        } else if (i < 672768) {
            int q = i - 665600;
            if (q < 2048) {
                int j = q & 7, l = (q >> 3) & 63, mf = q >> 9;
                int nn = mf * 16 + (l & 15);
                int ch = (l >> 4) * 8 + j;
                float v = ch < 16 ? mw1[ch * 64 + nn] : (ch == 16 ? mb1[nn] : 0.f);
                WPM1[q] = __float2bfloat16(v);
            } else if (q < 6144) {
                int p = q - 2048;
                int j = p & 7, l = (p >> 3) & 63, f = p >> 9;
                int kb = f >> 2, mf = f & 3;
                int nn = mf * 16 + (l & 15);
                int k = kb * 32 + (l >> 4) * 8 + j;
                WPM2[p] = __float2bfloat16(mw2[k * 64 + nn]);
            } else {
                int p = q - 6144;
                int j = p & 7, l = (p >> 3) & 63, kb = p >> 9;
                int m = l & 15;
                int k = kb * 32 + (l >> 4) * 8 + j;
                WPM3[p] = __float2bfloat16(m < 4 ? mw3[k * 4 + m] : 0.f);
            }
        }
        return;
    }

    // ---------- conv1 path (XCD-locality grid) ----------
    int xcd = b & 7, slot = b >> 3;
    int v = xcd + 8 * (slot >> 4);
    int oyb = slot & 15;
    if (v >= NVV) return;
    const float* ip = img + (size_t)v * 3 * 128 * 128;
    int iy0 = oyb * 8;
    for (int idx = tid; idx < 3456; idx += 256) {
        int ix = idx & 127;
        int t = idx >> 7;
        int iyl = t % 9, ic = t / 9;
        int iy = iy0 + iyl;
        tile[(ic * 9 + iyl) * 132 + ix] = (iy < 128) ? ip[(ic * 128 + iy) * 128 + ix] : 0.f;
    }
    if (tid < 108) {
        int c = tid & 3;
        int t = tid >> 2;
        int iyl = t % 9, ic = t / 9;
        tile[(ic * 9 + iyl) * 132 + 128 + c] = 0.f;
    }
    for (int i = tid; i < 1728; i += 256) w1s[i] = w1[i];
    __syncthreads();

    int l = tid & 63, w = tid >> 6;
    int lane16 = l & 15, lgrp = l >> 4;
    int oy = oyb * 4 + w;

    int offj[8];
    bool okj[8];
    #pragma unroll
    for (int j = 0; j < 8; ++j) {
        int k = lgrp * 8 + j;
        bool ok = k < 27;
        int kc = ok ? k : 0;
        int ic = kc / 9, r = kc % 9;
        int ky = r / 3, kx = r % 3;
        offj[j] = (ic * 9 + 2 * w + ky) * 132 + kx;
        okj[j] = ok;
    }

    bf16x8 a[4];
    #pragma unroll
    for (int mf = 0; mf < 4; ++mf) {
        #pragma unroll
        for (int j = 0; j < 8; ++j) {
            int k = lgrp * 8 + j;
            a[mf][j] = (k < 27) ? f2bf(w1s[(mf * 16 + lane16) * 27 + k]) : (short)0;
        }
    }

    f32x4 acc[4][4];
    #pragma unroll
    for (int mf = 0; mf < 4; ++mf)
        #pragma unroll
        for (int nf = 0; nf < 4; ++nf)
            acc[mf][nf] = (f32x4){0.f, 0.f, 0.f, 0.f};

    #pragma unroll
    for (int nf = 0; nf < 4; ++nf) {
        int ox = nf * 16 + lane16;
        bf16x8 bb;
        #pragma unroll
        for (int j = 0; j < 8; ++j) {
            float x = tile[offj[j] + 2 * ox];
            bb[j] = okj[j] ? f2bf(x) : (short)0;
        }
        #pragma unroll
        for (int mf = 0; mf < 4; ++mf)
            acc[mf][nf] = __builtin_amdgcn_mfma_f32_16x16x32_bf16(a[mf], bb, acc[mf][nf], 0, 0, 0);
    }

    #pragma unroll
    for (int mf = 0; mf < 4; ++mf) {
        #pragma unroll
        for (int nf = 0; nf < 4; ++nf) {
            int px = (v * 64 + oy) * 64 + nf * 16 + lane16;
            s16x4 sv;
            #pragma unroll
            for (int r = 0; r < 4; ++r) {
                int oc = mf * 16 + lgrp * 4 + r;
                sv[r] = f2bf(fmaxf(acc[mf][nf][r] + b1[oc], 0.f));
            }
            *(s16x4*)((short*)A1c + (size_t)px * 64 + mf * 16 + lgrp * 4) = sv;
        }
    }
}

// ---------------- conv2 implicit GEMM (fully unrolled K): 2 waves, 128 oc x 64 px ----------------
__global__ __launch_bounds__(128) void conv2_mfma(const __hip_bfloat16* __restrict__ A1c,
                                                  const __hip_bfloat16* __restrict__ wpack,
                                                  const float* __restrict__ b2,
                                                  __hip_bfloat16* __restrict__ A2c) {
    int b = blockIdx.x;
    int xcd = b & 7, slot = b >> 3;
    int v = xcd + 8 * (slot >> 4);
    int oyb = slot & 15;                  // 16 row-pairs
    if (v >= NVV) return;
    int tid = threadIdx.x;
    int l = tid & 63;
    int wm = tid >> 6;                    // 0..1 over oc halves
    int lane16 = l & 15, lgrp = l >> 4;

    int oxv[4], oyv[4];
    const short* pxb[4];
    bool rOOB[4], cOOB[4];
    const short* ibase = (const short*)A1c + (size_t)v * 64 * 64 * 64;
    #pragma unroll
    for (int nf = 0; nf < 4; ++nf) {
        int px = nf * 16 + lane16;        // 0..63
        int dy = px >> 5, ox = px & 31;
        oxv[nf] = ox;
        oyv[nf] = oyb * 2 + dy;
        pxb[nf] = ibase + ((size_t)(2 * oyv[nf]) * 64 + 2 * ox) * 64 + lgrp * 8;
        rOOB[nf] = (oyv[nf] == 31);
        cOOB[nf] = (ox == 31);
    }

    f32x4 acc[4][4];
    #pragma unroll
    for (int mf = 0; mf < 4; ++mf)
        #pragma unroll
        for (int nf = 0; nf < 4; ++nf)
            acc[mf][nf] = (f32x4){0.f, 0.f, 0.f, 0.f};

    const short* ab = (const short*)wpack + wm * 4 * 512 + l * 8;
    const bf16x8 bz = (bf16x8){0, 0, 0, 0, 0, 0, 0, 0};

    #pragma unroll
    for (int kk = 0; kk < 9; ++kk) {
        const int ky = kk / 3, kx = kk % 3;
        #pragma unroll
        for (int icb = 0; icb < 2; ++icb) {
            bf16x8 a[4];
            #pragma unroll
            for (int mf = 0; mf < 4; ++mf)
                a[mf] = *(const bf16x8*)(ab + ((kk * 2 + icb) * 8 + mf) * 512);

            bf16x8 bb[4];
            #pragma unroll
            for (int nf = 0; nf < 4; ++nf) {
                bf16x8 t = *(const bf16x8*)(pxb[nf] + (ky * 64 + kx) * 64 + icb * 32);
                bool dead = (ky == 2 && rOOB[nf]) || (kx == 2 && cOOB[nf]);
                bb[nf] = dead ? bz : t;
            }
            #pragma unroll
            for (int mf = 0; mf < 4; ++mf)
                #pragma unroll
                for (int nf = 0; nf < 4; ++nf)
                    acc[mf][nf] = __builtin_amdgcn_mfma_f32_16x16x32_bf16(a[mf], bb[nf], acc[mf][nf], 0, 0, 0);
        }
    }

    #pragma unroll
    for (int nf = 0; nf < 4; ++nf) {
        int pix = oyv[nf] * 32 + oxv[nf];
        short* ob = (short*)A2c + ((size_t)v * 1024 + pix) * 128 + wm * 64;
        #pragma unroll
        for (int mf = 0; mf < 4; ++mf) {
            f32x4 bv = *(const f32x4*)(b2 + wm * 64 + mf * 16 + lgrp * 4);
            s16x4 sv;
            #pragma unroll
            for (int r = 0; r < 4; ++r) sv[r] = f2bf(fmaxf(acc[mf][nf][r] + bv[r], 0.f));
            *(s16x4*)(ob + mf * 16 + lgrp * 4) = sv;
        }
    }
}

// ---------------- mean over views: A2c bf16 (50,1024,128) -> XBc bf16 (1024,128) ----------------
__global__ __launch_bounds__(256) void mean_kernel(const __hip_bfloat16* __restrict__ A2c,
                                                   __hip_bfloat16* __restrict__ XBc) {
    int i = blockIdx.x * 256 + threadIdx.x;   // 16384
    int g = i & 15, pix = i >> 4;
    float acc[8] = {0.f, 0.f, 0.f, 0.f, 0.f, 0.f, 0.f, 0.f};
    for (int v = 0; v < NVV; ++v) {
        bf16x8 x = *(const bf16x8*)((const short*)A2c + ((size_t)v * 1024 + pix) * 128 + g * 8);
        #pragma unroll
        for (int j = 0; j < 8; ++j) acc[j] += bf2f(x[j]);
    }
    bf16x8 o;
    #pragma unroll
    for (int j = 0; j < 8; ++j) o[j] = f2bf(acc[j] * (1.0f / NVV));
    *(bf16x8*)((short*)XBc + (size_t)pix * 128 + g * 8) = o;
}

// ---------------- conv3 implicit GEMM (fully unrolled K): grid (8 oc-tiles, 32 px-tiles), 2 waves ----------------
__global__ __launch_bounds__(128) void conv3_mfma(const __hip_bfloat16* __restrict__ XBc,
                                                  const __hip_bfloat16* __restrict__ wpack,
                                                  const float* __restrict__ b3,
                                                  __hip_bfloat16* __restrict__ VOLc) {
    int tid = threadIdx.x;
    int l = tid & 63;
    int wn = tid >> 6;
    int lane16 = l & 15, lgrp = l >> 4;

    int px = blockIdx.y * 32 + wn * 16 + lane16;
    int y = px >> 5, x = px & 31;

    const short* pxb = (const short*)XBc + ((ptrdiff_t)(y - 1) * 32 + (x - 1)) * 128 + lgrp * 8;
    bool tOOB = (y == 0), bOOB = (y == 31), lOOB = (x == 0), rOOB = (x == 31);

    f32x4 acc[4];
    #pragma unroll
    for (int mf = 0; mf < 4; ++mf) acc[mf] = (f32x4){0.f, 0.f, 0.f, 0.f};

    const short* ab = (const short*)wpack + (size_t)blockIdx.x * 4 * 512 + l * 8;
    const bf16x8 bzv = (bf16x8){0, 0, 0, 0, 0, 0, 0, 0};

    #pragma unroll
    for (int kk = 0; kk < 9; ++kk) {
        const int ky = kk / 3, kx = kk % 3;
        bool dead = (ky == 0 && tOOB) || (ky == 2 && bOOB) || (kx == 0 && lOOB) || (kx == 2 && rOOB);
        #pragma unroll
        for (int icb = 0; icb < 4; ++icb) {
            bf16x8 t = *(const bf16x8*)(pxb + (ky * 32 + kx) * 128 + icb * 32);
            bf16x8 bb = dead ? bzv : t;
            #pragma unroll
            for (int mf = 0; mf < 4; ++mf) {
                bf16x8 a = *(const bf16x8*)(ab + (size_t)((kk * 4 + icb) * 32 + mf) * 512);
                acc[mf] = __builtin_amdgcn_mfma_f32_16x16x32_bf16(a, bb, acc[mf], 0, 0, 0);
            }
        }
    }

    int oc_base = blockIdx.x * 64;
    #pragma unroll
    for (int mf = 0; mf < 4; ++mf) {
        f32x4 bv = *(const f32x4*)(b3 + oc_base + mf * 16 + lgrp * 4);
        #pragma unroll
        for (int r = 0; r < 4; ++r) {
            int oc = oc_base + mf * 16 + lgrp * 4 + r;
            int c = oc >> 5, iz = oc & 31;
            VOLc[((size_t)((iz * 32 + y) * 32 + x)) * 16 + c] = __float2bfloat16(acc[mf][r] + bv[r]);
        }
    }
}

// ---------------- fused trilinear + MLP + volume render: wave = 1 pixel x 64 samples ----------------
__global__ __launch_bounds__(256) void mlp_render(const __hip_bfloat16* __restrict__ VOLc,
                                                  const float* __restrict__ rays,
                                                  const __hip_bfloat16* __restrict__ wpm1,
                                                  const __hip_bfloat16* __restrict__ wpm2,
                                                  const __hip_bfloat16* __restrict__ wpm3,
                                                  const float* __restrict__ mb2,
                                                  const float* __restrict__ mb3,
                                                  float* __restrict__ out) {
    __shared__ short hbuf[4][32 * 72];
    __shared__ f32x4 rawb[4][64];
    int tid = threadIdx.x;
    int w = tid >> 6, l = tid & 63;
    int lane16 = l & 15, lgrp = l >> 4;
    short* hb = hbuf[w];
    int pix = blockIdx.x * 4 + w;          // wave-uniform pixel

    bf16x8 a1[4];
    #pragma unroll
    for (int mf = 0; mf < 4; ++mf)
        a1[mf] = *(const bf16x8*)((const short*)wpm1 + (mf * 64 + l) * 8);
    bf16x8 a2[2][4];
    #pragma unroll
    for (int kb = 0; kb < 2; ++kb)
        #pragma unroll
        for (int mf = 0; mf < 4; ++mf)
            a2[kb][mf] = *(const bf16x8*)((const short*)wpm2 + ((kb * 4 + mf) * 64 + l) * 8);
    bf16x8 a3[2];
    a3[0] = *(const bf16x8*)((const short*)wpm3 + (0 * 64 + l) * 8);
    a3[1] = *(const bf16x8*)((const short*)wpm3 + (1 * 64 + l) * 8);
    f32x4 b3v = *(const f32x4*)(mb3);

    const bf16x8 bz = (bf16x8){0, 0, 0, 0, 0, 0, 0, 0};
    const bf16x8 bbias = (bf16x8){(short)0x3F80, 0, 0, 0, 0, 0, 0, 0};

    float o0 = rays[pix], o1 = rays[4096 + pix], o2 = rays[2 * 4096 + pix];
    float d0 = rays[3 * 4096 + pix], d1 = rays[4 * 4096 + pix], d2 = rays[5 * 4096 + pix];
    float nearv = rays[6 * 4096 + pix], farv = rays[7 * 4096 + pix];

    int nfg = l >> 5, hf = (l >> 4) & 1;

    for (int rep = 0; rep < 2; ++rep) {
        int s = rep * 32 + nfg * 16 + lane16;
        float t = (float)s / 63.0f;
        float z = nearv + (farv - nearv) * t;
        float px = o0 + d0 * z, py = o1 + d1 * z, pz = o2 + d2 * z;
        float cx = fminf(fmaxf((px + 1.f) * 15.5f, 0.f), 31.f);
        float cy = fminf(fmaxf((py + 1.f) * 15.5f, 0.f), 31.f);
        float cz = fminf(fmaxf((pz + 1.f) * 15.5f, 0.f), 31.f);
        int ix = min((int)floorf(cx), 30);
        int iy = min((int)floorf(cy), 30);
        int iz = min((int)floorf(cz), 30);
        float fx = cx - (float)ix, fy = cy - (float)iy, fz = cz - (float)iz;
        float gx = 1.f - fx, gy = 1.f - fy, gz = 1.f - fz;
        float wv[8] = {gz * gy * gx, gz * gy * fx, gz * fy * gx, gz * fy * fx,
                       fz * gy * gx, fz * gy * fx, fz * fy * gx, fz * fy * fx};
        const int co[8] = {0, 16, 512, 528, 16384, 16400, 16896, 16912};
        int base = (iz * 32 + iy) * 32 + ix;
        const short* vp = (const short*)VOLc + (size_t)base * 16 + hf * 8;

        float f8[8] = {0.f, 0.f, 0.f, 0.f, 0.f, 0.f, 0.f, 0.f};
        #pragma unroll
        for (int c = 0; c < 8; ++c) {
            bf16x8 cv = *(const bf16x8*)(vp + co[c]);
            #pragma unroll
            for (int j = 0; j < 8; ++j) f8[j] += wv[c] * bf2f(cv[j]);
        }
        bf16x8 own;
        #pragma unroll
        for (int j = 0; j < 8; ++j) own[j] = f2bf(f8[j]);

        i32x4 oi = __builtin_bit_cast(i32x4, own);
        i32x4 si;
        si[0] = __shfl_xor(oi[0], 32);
        si[1] = __shfl_xor(oi[1], 32);
        si[2] = __shfl_xor(oi[2], 32);
        si[3] = __shfl_xor(oi[3], 32);
        bf16x8 swf = __builtin_bit_cast(bf16x8, si);

        bf16x8 b0 = (lgrp < 2) ? own : ((lgrp == 2) ? bbias : bz);
        bf16x8 b1 = (lgrp < 2) ? swf : ((lgrp == 2) ? bbias : bz);

        f32x4 acc1[4][2];
        #pragma unroll
        for (int mf = 0; mf < 4; ++mf) {
            acc1[mf][0] = (f32x4){0.f, 0.f, 0.f, 0.f};
            acc1[mf][1] = (f32x4){0.f, 0.f, 0.f, 0.f};
            acc1[mf][0] = __builtin_amdgcn_mfma_f32_16x16x32_bf16(a1[mf], b0, acc1[mf][0], 0, 0, 0);
            acc1[mf][1] = __builtin_amdgcn_mfma_f32_16x16x32_bf16(a1[mf], b1, acc1[mf][1], 0, 0, 0);
        }
        #pragma unroll
        for (int mf = 0; mf < 4; ++mf) {
            #pragma unroll
            for (int nf = 0; nf < 2; ++nf) {
                s16x4 sv;
                #pragma unroll
                for (int r = 0; r < 4; ++r) sv[r] = f2bf(fmaxf(acc1[mf][nf][r], 0.f));
                *(s16x4*)(hb + (nf * 16 + lane16) * 72 + mf * 16 + lgrp * 4) = sv;
            }
        }

        f32x4 acc2[4][2];
        #pragma unroll
        for (int mf = 0; mf < 4; ++mf) {
            acc2[mf][0] = (f32x4){0.f, 0.f, 0.f, 0.f};
            acc2[mf][1] = (f32x4){0.f, 0.f, 0.f, 0.f};
        }
        #pragma unroll
        for (int nf = 0; nf < 2; ++nf) {
            #pragma unroll
            for (int kb = 0; kb < 2; ++kb) {
                bf16x8 bh = *(const bf16x8*)(hb + (nf * 16 + lane16) * 72 + kb * 32 + lgrp * 8);
                #pragma unroll
                for (int mf = 0; mf < 4; ++mf)
                    acc2[mf][nf] = __builtin_amdgcn_mfma_f32_16x16x32_bf16(a2[kb][mf], bh, acc2[mf][nf], 0, 0, 0);
            }
        }
        #pragma unroll
        for (int mf = 0; mf < 4; ++mf) {
            f32x4 bv = *(const f32x4*)(mb2 + mf * 16 + lgrp * 4);
            #pragma unroll
            for (int nf = 0; nf < 2; ++nf) {
                s16x4 sv;
                #pragma unroll
                for (int r = 0; r < 4; ++r) sv[r] = f2bf(fmaxf(acc2[mf][nf][r] + bv[r], 0.f));
                *(s16x4*)(hb + (nf * 16 + lane16) * 72 + mf * 16 + lgrp * 4) = sv;
            }
        }

        f32x4 acc3[2];
        acc3[0] = (f32x4){0.f, 0.f, 0.f, 0.f};
        acc3[1] = (f32x4){0.f, 0.f, 0.f, 0.f};
        #pragma unroll
        for (int nf = 0; nf < 2; ++nf) {
            #pragma unroll
            for (int kb = 0; kb < 2; ++kb) {
                bf16x8 bh = *(const bf16x8*)(hb + (nf * 16 + lane16) * 72 + kb * 32 + lgrp * 8);
                acc3[nf] = __builtin_amdgcn_mfma_f32_16x16x32_bf16(a3[kb], bh, acc3[nf], 0, 0, 0);
            }
        }
        if (lgrp == 0) {
            #pragma unroll
            for (int nf = 0; nf < 2; ++nf)
                rawb[w][rep * 32 + nf * 16 + lane16] = acc3[nf] + b3v;
        }
    }

    // ---- wave-parallel volume rendering ----
    f32x4 rv = rawb[w][l];
    float dz = (farv - nearv) * (1.f / 63.f);
    float zl = nearv + (farv - nearv) * ((float)l / 63.0f);
    float delta = (l == 63) ? 1e10f : dz;
    float sigma = fmaxf(rv[3], 0.f);
    float alpha = 1.f - __expf(-sigma * delta);
    float la = __builtin_log2f(1.f - alpha + 1e-10f);

    float inc = la;
    #pragma unroll
    for (int off = 1; off < 64; off <<= 1) {
        float y = __shfl_up(inc, off);
        if (l >= off) inc += y;
    }
    float T = __builtin_exp2f(inc - la);
    float wt = alpha * T;

    float cr = wt / (1.f + __expf(-rv[0]));
    float cg = wt / (1.f + __expf(-rv[1]));
    float cb = wt / (1.f + __expf(-rv[2]));
    float cd = wt * zl;

    #pragma unroll
    for (int off = 32; off > 0; off >>= 1) {
        cr += __shfl_down(cr, off);
        cg += __shfl_down(cg, off);
        cb += __shfl_down(cb, off);
        cd += __shfl_down(cd, off);
    }
    if (l == 0) {
        out[pix]             = cr;
        out[4096 + pix]      = cg;
        out[2 * 4096 + pix]  = cb;
        out[12288 + pix]     = cd;
    }
}

extern "C" void kernel_launch(void* const* d_in, const int* in_sizes, int n_in,
                              void* d_out, int out_size, void* d_ws, size_t ws_size,
                              hipStream_t stream) {
    const float* images = (const float*)d_in[0];
    const float* rays   = (const float*)d_in[1];
    const float* w1 = (const float*)d_in[2];
    const float* b1 = (const float*)d_in[3];
    const float* w2 = (const float*)d_in[4];
    const float* b2 = (const float*)d_in[5];
    const float* w3 = (const float*)d_in[6];
    const float* b3 = (const float*)d_in[7];
    const float* mw1 = (const float*)d_in[8];
    const float* mb1 = (const float*)d_in[9];
    const float* mw2 = (const float*)d_in[10];
    const float* mb2 = (const float*)d_in[11];
    const float* mw3 = (const float*)d_in[12];
    const float* mb3 = (const float*)d_in[13];
    float* out = (float*)d_out;

    // workspace layout (bf16 region)
    __hip_bfloat16* A1c  = (__hip_bfloat16*)d_ws;              // 13107200 bf16
    __hip_bfloat16* WPK2 = A1c + 13107200;                     // 73728
    __hip_bfloat16* WPK1 = WPK2 + 73728;                       // 2048 (retired, kept for layout)
    __hip_bfloat16* VOLc = WPK1 + 2048;                        // 524288
    __hip_bfloat16* WPM1 = VOLc + 524288;                      // 2048
    __hip_bfloat16* WPM2 = WPM1 + 2048;                        // 4096
    __hip_bfloat16* WPM3 = WPM2 + 4096;                        // 1024
    __hip_bfloat16* A2c  = WPM3 + 1024;                        // 6553600
    __hip_bfloat16* XBc  = A2c + 6553600;                      // 131072
    __hip_bfloat16* WPK3 = XBc + 131072;                       // 589824

    conv1_pack<<<dim3(3524), dim3(256), 0, stream>>>(images, w1, b1, w2, w3, mw1, mb1, mw2, mw3,
                                                     A1c, WPK2, WPK3, WPM1, WPM2, WPM3);
    conv2_mfma<<<dim3(896), dim3(128), 0, stream>>>(A1c, WPK2, b2, A2c);
    mean_kernel<<<dim3(64), dim3(256), 0, stream>>>(A2c, XBc);
    conv3_mfma<<<dim3(8, 32), dim3(128), 0, stream>>>(XBc, WPK3, b3, VOLc);
    mlp_render<<<dim3(1024), dim3(256), 0, stream>>>(VOLc, rays, WPM1, WPM2, WPM3, mb2, mb3, out);
}

// Round 13
// 83.184 us; speedup vs baseline: 2.0825x; 1.0012x over previous
//
#include <hip/hip_runtime.h>
#include <hip/hip_bf16.h>

#define NVV 50
#define C1 64
#define C2 128
#define HW1 64
#define HW2 32

typedef short bf16x8 __attribute__((ext_vector_type(8)));
typedef short s16x4 __attribute__((ext_vector_type(4)));
typedef float f32x4 __attribute__((ext_vector_type(4)));
typedef int i32x4 __attribute__((ext_vector_type(4)));

__device__ inline short f2bf(float x) {
    unsigned u = __builtin_bit_cast(unsigned, x);
    unsigned r = (u + 0x7FFFu + ((u >> 16) & 1u)) >> 16;
    return (short)r;
}
__device__ inline float bf2f(short x) {
    unsigned u = ((unsigned)(unsigned short)x) << 16;
    return __builtin_bit_cast(float, u);
}

// ---------------- kernel 1: conv1 (blocks 0..895) + weight packing (blocks 896..3523) ----------------
__global__ __launch_bounds__(256) void conv1_pack(const float* __restrict__ img,
                                                  const float* __restrict__ w1,
                                                  const float* __restrict__ b1,
                                                  const float* __restrict__ w2,
                                                  const float* __restrict__ w3,
                                                  const float* __restrict__ mw1, const float* __restrict__ mb1,
                                                  const float* __restrict__ mw2, const float* __restrict__ mw3,
                                                  __hip_bfloat16* __restrict__ A1c,
                                                  __hip_bfloat16* __restrict__ WPK2,
                                                  __hip_bfloat16* __restrict__ WPK3,
                                                  __hip_bfloat16* __restrict__ WPM1,
                                                  __hip_bfloat16* __restrict__ WPM2,
                                                  __hip_bfloat16* __restrict__ WPM3) {
    __shared__ float tile[3 * 9 * 132];
    __shared__ float w1s[1728];
    int b = blockIdx.x;
    int tid = threadIdx.x;

    if (b >= 896) {
        int i = (b - 896) * 256 + tid;
        if (i < 2048) {
            // retired
        } else if (i < 75776) {
            int q = i - 2048;
            int j = q & 7, l = (q >> 3) & 63;
            int rest = q >> 9;
            int mtile = rest & 7;
            rest >>= 3;
            int icb = rest & 1;
            int kk = rest >> 1;
            int oc = mtile * 16 + (l & 15);
            int ic = icb * 32 + (l >> 4) * 8 + j;
            int ky = kk / 3, kx = kk % 3;
            WPK2[q] = __float2bfloat16(w2[((oc * 64 + ic) * 3 + ky) * 3 + kx]);
        } else if (i < 665600) {
            int q = i - 75776;
            int j = q & 7, l = (q >> 3) & 63;
            int rest = q >> 9;
            int m = rest & 31;
            rest >>= 5;
            int icb = rest & 3;
            int kk = rest >> 2;
            int oc = m * 16 + (l & 15);
            int ic = icb * 32 + (l >> 4) * 8 + j;
            int ky = kk / 3, kx = kk % 3;
            WPK3[q] = __float2bfloat16(w3[((oc * 128 + ic) * 3 + ky) * 3 + kx]);
        } else if (i < 672768) {
            int q = i - 665600;
            if (q < 2048) {
                int j = q & 7, l = (q >> 3) & 63, mf = q >> 9;
                int nn = mf * 16 + (l & 15);
                int ch = (l >> 4) * 8 + j;
                float v = ch < 16 ? mw1[ch * 64 + nn] : (ch == 16 ? mb1[nn] : 0.f);
                WPM1[q] = __float2bfloat16(v);
            } else if (q < 6144) {
                int p = q - 2048;
                int j = p & 7, l = (p >> 3) & 63, f = p >> 9;
                int kb = f >> 2, mf = f & 3;
                int nn = mf * 16 + (l & 15);
                int k = kb * 32 + (l >> 4) * 8 + j;
                WPM2[p] = __float2bfloat16(mw2[k * 64 + nn]);
            } else {
                int p = q - 6144;
                int j = p & 7, l = (p >> 3) & 63, kb = p >> 9;
                int m = l & 15;
                int k = kb * 32 + (l >> 4) * 8 + j;
                WPM3[p] = __float2bfloat16(m < 4 ? mw3[k * 4 + m] : 0.f);
            }
        }
        return;
    }

    // ---------- conv1 path (XCD-locality grid) ----------
    int xcd = b & 7, slot = b >> 3;
    int v = xcd + 8 * (slot >> 4);
    int oyb = slot & 15;
    if (v >= NVV) return;
    const float* ip = img + (size_t)v * 3 * 128 * 128;
    int iy0 = oyb * 8;
    for (int idx = tid; idx < 3456; idx += 256) {
        int ix = idx & 127;
        int t = idx >> 7;
        int iyl = t % 9, ic = t / 9;
        int iy = iy0 + iyl;
        tile[(ic * 9 + iyl) * 132 + ix] = (iy < 128) ? ip[(ic * 128 + iy) * 128 + ix] : 0.f;
    }
    if (tid < 108) {
        int c = tid & 3;
        int t = tid >> 2;
        int iyl = t % 9, ic = t / 9;
        tile[(ic * 9 + iyl) * 132 + 128 + c] = 0.f;
    }
    for (int i = tid; i < 1728; i += 256) w1s[i] = w1[i];
    __syncthreads();

    int l = tid & 63, w = tid >> 6;
    int lane16 = l & 15, lgrp = l >> 4;
    int oy = oyb * 4 + w;

    int offj[8];
    bool okj[8];
    #pragma unroll
    for (int j = 0; j < 8; ++j) {
        int k = lgrp * 8 + j;
        bool ok = k < 27;
        int kc = ok ? k : 0;
        int ic = kc / 9, r = kc % 9;
        int ky = r / 3, kx = r % 3;
        offj[j] = (ic * 9 + 2 * w + ky) * 132 + kx;
        okj[j] = ok;
    }

    bf16x8 a[4];
    #pragma unroll
    for (int mf = 0; mf < 4; ++mf) {
        #pragma unroll
        for (int j = 0; j < 8; ++j) {
            int k = lgrp * 8 + j;
            a[mf][j] = (k < 27) ? f2bf(w1s[(mf * 16 + lane16) * 27 + k]) : (short)0;
        }
    }

    f32x4 acc[4][4];
    #pragma unroll
    for (int mf = 0; mf < 4; ++mf)
        #pragma unroll
        for (int nf = 0; nf < 4; ++nf)
            acc[mf][nf] = (f32x4){0.f, 0.f, 0.f, 0.f};

    #pragma unroll
    for (int nf = 0; nf < 4; ++nf) {
        int ox = nf * 16 + lane16;
        bf16x8 bb;
        #pragma unroll
        for (int j = 0; j < 8; ++j) {
            float x = tile[offj[j] + 2 * ox];
            bb[j] = okj[j] ? f2bf(x) : (short)0;
        }
        #pragma unroll
        for (int mf = 0; mf < 4; ++mf)
            acc[mf][nf] = __builtin_amdgcn_mfma_f32_16x16x32_bf16(a[mf], bb, acc[mf][nf], 0, 0, 0);
    }

    #pragma unroll
    for (int mf = 0; mf < 4; ++mf) {
        #pragma unroll
        for (int nf = 0; nf < 4; ++nf) {
            int px = (v * 64 + oy) * 64 + nf * 16 + lane16;
            s16x4 sv;
            #pragma unroll
            for (int r = 0; r < 4; ++r) {
                int oc = mf * 16 + lgrp * 4 + r;
                sv[r] = f2bf(fmaxf(acc[mf][nf][r] + b1[oc], 0.f));
            }
            *(s16x4*)((short*)A1c + (size_t)px * 64 + mf * 16 + lgrp * 4) = sv;
        }
    }
}

// ---------------- conv2 implicit GEMM: block = 128 oc x 32 px (one output row), 2 waves ----------------
// grid 1792 = 8 xcd * 32 rows * 7; XCD-local per view.
__global__ __launch_bounds__(128) void conv2_mfma(const __hip_bfloat16* __restrict__ A1c,
                                                  const __hip_bfloat16* __restrict__ wpack,
                                                  const float* __restrict__ b2,
                                                  __hip_bfloat16* __restrict__ A2c) {
    int b = blockIdx.x;
    int xcd = b & 7, slot = b >> 3;
    int v = xcd + 8 * (slot >> 5);
    int oy = slot & 31;                   // output row 0..31
    if (v >= NVV) return;
    int tid = threadIdx.x;
    int l = tid & 63;
    int wm = tid >> 6;                    // 0..1 over oc halves
    int lane16 = l & 15, lgrp = l >> 4;

    int oxv[2];
    const short* pxb[2];
    bool cOOB[2];
    bool rOOB = (oy == 31);
    const short* ibase = (const short*)A1c + (size_t)v * 64 * 64 * 64;
    #pragma unroll
    for (int nf = 0; nf < 2; ++nf) {
        int ox = nf * 16 + lane16;        // 0..31
        oxv[nf] = ox;
        pxb[nf] = ibase + ((size_t)(2 * oy) * 64 + 2 * ox) * 64 + lgrp * 8;
        cOOB[nf] = (ox == 31);
    }

    f32x4 acc[4][2];
    #pragma unroll
    for (int mf = 0; mf < 4; ++mf)
        #pragma unroll
        for (int nf = 0; nf < 2; ++nf)
            acc[mf][nf] = (f32x4){0.f, 0.f, 0.f, 0.f};

    const short* ab = (const short*)wpack + wm * 4 * 512 + l * 8;
    const bf16x8 bz = (bf16x8){0, 0, 0, 0, 0, 0, 0, 0};

    #pragma unroll
    for (int kk = 0; kk < 9; ++kk) {
        const int ky = kk / 3, kx = kk % 3;
        #pragma unroll
        for (int icb = 0; icb < 2; ++icb) {
            bf16x8 a[4];
            #pragma unroll
            for (int mf = 0; mf < 4; ++mf)
                a[mf] = *(const bf16x8*)(ab + ((kk * 2 + icb) * 8 + mf) * 512);

            bf16x8 bb[2];
            #pragma unroll
            for (int nf = 0; nf < 2; ++nf) {
                bf16x8 t = *(const bf16x8*)(pxb[nf] + (ky * 64 + kx) * 64 + icb * 32);
                bool dead = (ky == 2 && rOOB) || (kx == 2 && cOOB[nf]);
                bb[nf] = dead ? bz : t;
            }
            #pragma unroll
            for (int mf = 0; mf < 4; ++mf)
                #pragma unroll
                for (int nf = 0; nf < 2; ++nf)
                    acc[mf][nf] = __builtin_amdgcn_mfma_f32_16x16x32_bf16(a[mf], bb[nf], acc[mf][nf], 0, 0, 0);
        }
    }

    #pragma unroll
    for (int nf = 0; nf < 2; ++nf) {
        int pix = oy * 32 + oxv[nf];
        short* ob = (short*)A2c + ((size_t)v * 1024 + pix) * 128 + wm * 64;
        #pragma unroll
        for (int mf = 0; mf < 4; ++mf) {
            f32x4 bv = *(const f32x4*)(b2 + wm * 64 + mf * 16 + lgrp * 4);
            s16x4 sv;
            #pragma unroll
            for (int r = 0; r < 4; ++r) sv[r] = f2bf(fmaxf(acc[mf][nf][r] + bv[r], 0.f));
            *(s16x4*)(ob + mf * 16 + lgrp * 4) = sv;
        }
    }
}

// ---------------- mean over views: A2c bf16 (50,1024,128) -> XBc bf16 (1024,128) ----------------
__global__ __launch_bounds__(64) void mean_kernel(const __hip_bfloat16* __restrict__ A2c,
                                                  __hip_bfloat16* __restrict__ XBc) {
    int i = blockIdx.x * 64 + threadIdx.x;    // 16384
    int g = i & 15, pix = i >> 4;
    float acc[8] = {0.f, 0.f, 0.f, 0.f, 0.f, 0.f, 0.f, 0.f};
    for (int v = 0; v < NVV; ++v) {
        bf16x8 x = *(const bf16x8*)((const short*)A2c + ((size_t)v * 1024 + pix) * 128 + g * 8);
        #pragma unroll
        for (int j = 0; j < 8; ++j) acc[j] += bf2f(x[j]);
    }
    bf16x8 o;
    #pragma unroll
    for (int j = 0; j < 8; ++j) o[j] = f2bf(acc[j] * (1.0f / NVV));
    *(bf16x8*)((short*)XBc + (size_t)pix * 128 + g * 8) = o;
}

// ---------------- conv3 implicit GEMM: block = 32 oc x 32 px, grid (16,32), 2 waves ----------------
__global__ __launch_bounds__(128) void conv3_mfma(const __hip_bfloat16* __restrict__ XBc,
                                                  const __hip_bfloat16* __restrict__ wpack,
                                                  const float* __restrict__ b3,
                                                  __hip_bfloat16* __restrict__ VOLc) {
    int tid = threadIdx.x;
    int l = tid & 63;
    int wn = tid >> 6;
    int lane16 = l & 15, lgrp = l >> 4;

    int px = blockIdx.y * 32 + wn * 16 + lane16;
    int y = px >> 5, x = px & 31;

    const short* pxb = (const short*)XBc + ((ptrdiff_t)(y - 1) * 32 + (x - 1)) * 128 + lgrp * 8;
    bool tOOB = (y == 0), bOOB = (y == 31), lOOB = (x == 0), rOOB = (x == 31);

    f32x4 acc[2];
    acc[0] = (f32x4){0.f, 0.f, 0.f, 0.f};
    acc[1] = (f32x4){0.f, 0.f, 0.f, 0.f};

    // wpack layout: [kk][icb][mtile32][lane][8]; this block's mtiles = bx*2 + mf
    const short* ab = (const short*)wpack + (size_t)blockIdx.x * 2 * 512 + l * 8;
    const bf16x8 bzv = (bf16x8){0, 0, 0, 0, 0, 0, 0, 0};

    #pragma unroll
    for (int kk = 0; kk < 9; ++kk) {
        const int ky = kk / 3, kx = kk % 3;
        bool dead = (ky == 0 && tOOB) || (ky == 2 && bOOB) || (kx == 0 && lOOB) || (kx == 2 && rOOB);
        #pragma unroll
        for (int icb = 0; icb < 4; ++icb) {
            bf16x8 t = *(const bf16x8*)(pxb + (ky * 32 + kx) * 128 + icb * 32);
            bf16x8 bb = dead ? bzv : t;
            #pragma unroll
            for (int mf = 0; mf < 2; ++mf) {
                bf16x8 a = *(const bf16x8*)(ab + (size_t)((kk * 4 + icb) * 32 + mf) * 512);
                acc[mf] = __builtin_amdgcn_mfma_f32_16x16x32_bf16(a, bb, acc[mf], 0, 0, 0);
            }
        }
    }

    int oc_base = blockIdx.x * 32;
    #pragma unroll
    for (int mf = 0; mf < 2; ++mf) {
        f32x4 bv = *(const f32x4*)(b3 + oc_base + mf * 16 + lgrp * 4);
        #pragma unroll
        for (int r = 0; r < 4; ++r) {
            int oc = oc_base + mf * 16 + lgrp * 4 + r;
            int c = oc >> 5, iz = oc & 31;
            VOLc[((size_t)((iz * 32 + y) * 32 + x)) * 16 + c] = __float2bfloat16(acc[mf][r] + bv[r]);
        }
    }
}

// ---------------- fused trilinear + MLP + volume render: wave = 1 pixel x 64 samples ----------------
__global__ __launch_bounds__(256) void mlp_render(const __hip_bfloat16* __restrict__ VOLc,
                                                  const float* __restrict__ rays,
                                                  const __hip_bfloat16* __restrict__ wpm1,
                                                  const __hip_bfloat16* __restrict__ wpm2,
                                                  const __hip_bfloat16* __restrict__ wpm3,
                                                  const float* __restrict__ mb2,
                                                  const float* __restrict__ mb3,
                                                  float* __restrict__ out) {
    __shared__ short hbuf[4][32 * 72];
    __shared__ f32x4 rawb[4][64];
    int tid = threadIdx.x;
    int w = tid >> 6, l = tid & 63;
    int lane16 = l & 15, lgrp = l >> 4;
    short* hb = hbuf[w];
    int pix = blockIdx.x * 4 + w;          // wave-uniform pixel

    bf16x8 a1[4];
    #pragma unroll
    for (int mf = 0; mf < 4; ++mf)
        a1[mf] = *(const bf16x8*)((const short*)wpm1 + (mf * 64 + l) * 8);
    bf16x8 a2[2][4];
    #pragma unroll
    for (int kb = 0; kb < 2; ++kb)
        #pragma unroll
        for (int mf = 0; mf < 4; ++mf)
            a2[kb][mf] = *(const bf16x8*)((const short*)wpm2 + ((kb * 4 + mf) * 64 + l) * 8);
    bf16x8 a3[2];
    a3[0] = *(const bf16x8*)((const short*)wpm3 + (0 * 64 + l) * 8);
    a3[1] = *(const bf16x8*)((const short*)wpm3 + (1 * 64 + l) * 8);
    f32x4 b3v = *(const f32x4*)(mb3);

    const bf16x8 bz = (bf16x8){0, 0, 0, 0, 0, 0, 0, 0};
    const bf16x8 bbias = (bf16x8){(short)0x3F80, 0, 0, 0, 0, 0, 0, 0};

    float o0 = rays[pix], o1 = rays[4096 + pix], o2 = rays[2 * 4096 + pix];
    float d0 = rays[3 * 4096 + pix], d1 = rays[4 * 4096 + pix], d2 = rays[5 * 4096 + pix];
    float nearv = rays[6 * 4096 + pix], farv = rays[7 * 4096 + pix];

    int nfg = l >> 5, hf = (l >> 4) & 1;

    for (int rep = 0; rep < 2; ++rep) {
        int s = rep * 32 + nfg * 16 + lane16;
        float t = (float)s / 63.0f;
        float z = nearv + (farv - nearv) * t;
        float px = o0 + d0 * z, py = o1 + d1 * z, pz = o2 + d2 * z;
        float cx = fminf(fmaxf((px + 1.f) * 15.5f, 0.f), 31.f);
        float cy = fminf(fmaxf((py + 1.f) * 15.5f, 0.f), 31.f);
        float cz = fminf(fmaxf((pz + 1.f) * 15.5f, 0.f), 31.f);
        int ix = min((int)floorf(cx), 30);
        int iy = min((int)floorf(cy), 30);
        int iz = min((int)floorf(cz), 30);
        float fx = cx - (float)ix, fy = cy - (float)iy, fz = cz - (float)iz;
        float gx = 1.f - fx, gy = 1.f - fy, gz = 1.f - fz;
        float wv[8] = {gz * gy * gx, gz * gy * fx, gz * fy * gx, gz * fy * fx,
                       fz * gy * gx, fz * gy * fx, fz * fy * gx, fz * fy * fx};
        const int co[8] = {0, 16, 512, 528, 16384, 16400, 16896, 16912};
        int base = (iz * 32 + iy) * 32 + ix;
        const short* vp = (const short*)VOLc + (size_t)base * 16 + hf * 8;

        float f8[8] = {0.f, 0.f, 0.f, 0.f, 0.f, 0.f, 0.f, 0.f};
        #pragma unroll
        for (int c = 0; c < 8; ++c) {
            bf16x8 cv = *(const bf16x8*)(vp + co[c]);
            #pragma unroll
            for (int j = 0; j < 8; ++j) f8[j] += wv[c] * bf2f(cv[j]);
        }
        bf16x8 own;
        #pragma unroll
        for (int j = 0; j < 8; ++j) own[j] = f2bf(f8[j]);

        i32x4 oi = __builtin_bit_cast(i32x4, own);
        i32x4 si;
        si[0] = __shfl_xor(oi[0], 32);
        si[1] = __shfl_xor(oi[1], 32);
        si[2] = __shfl_xor(oi[2], 32);
        si[3] = __shfl_xor(oi[3], 32);
        bf16x8 swf = __builtin_bit_cast(bf16x8, si);

        bf16x8 b0 = (lgrp < 2) ? own : ((lgrp == 2) ? bbias : bz);
        bf16x8 b1 = (lgrp < 2) ? swf : ((lgrp == 2) ? bbias : bz);

        f32x4 acc1[4][2];
        #pragma unroll
        for (int mf = 0; mf < 4; ++mf) {
            acc1[mf][0] = (f32x4){0.f, 0.f, 0.f, 0.f};
            acc1[mf][1] = (f32x4){0.f, 0.f, 0.f, 0.f};
            acc1[mf][0] = __builtin_amdgcn_mfma_f32_16x16x32_bf16(a1[mf], b0, acc1[mf][0], 0, 0, 0);
            acc1[mf][1] = __builtin_amdgcn_mfma_f32_16x16x32_bf16(a1[mf], b1, acc1[mf][1], 0, 0, 0);
        }
        #pragma unroll
        for (int mf = 0; mf < 4; ++mf) {
            #pragma unroll
            for (int nf = 0; nf < 2; ++nf) {
                s16x4 sv;
                #pragma unroll
                for (int r = 0; r < 4; ++r) sv[r] = f2bf(fmaxf(acc1[mf][nf][r], 0.f));
                *(s16x4*)(hb + (nf * 16 + lane16) * 72 + mf * 16 + lgrp * 4) = sv;
            }
        }

        f32x4 acc2[4][2];
        #pragma unroll
        for (int mf = 0; mf < 4; ++mf) {
            acc2[mf][0] = (f32x4){0.f, 0.f, 0.f, 0.f};
            acc2[mf][1] = (f32x4){0.f, 0.f, 0.f, 0.f};
        }
        #pragma unroll
        for (int nf = 0; nf < 2; ++nf) {
            #pragma unroll
            for (int kb = 0; kb < 2; ++kb) {
                bf16x8 bh = *(const bf16x8*)(hb + (nf * 16 + lane16) * 72 + kb * 32 + lgrp * 8);
                #pragma unroll
                for (int mf = 0; mf < 4; ++mf)
                    acc2[mf][nf] = __builtin_amdgcn_mfma_f32_16x16x32_bf16(a2[kb][mf], bh, acc2[mf][nf], 0, 0, 0);
            }
        }
        #pragma unroll
        for (int mf = 0; mf < 4; ++mf) {
            f32x4 bv = *(const f32x4*)(mb2 + mf * 16 + lgrp * 4);
            #pragma unroll
            for (int nf = 0; nf < 2; ++nf) {
                s16x4 sv;
                #pragma unroll
                for (int r = 0; r < 4; ++r) sv[r] = f2bf(fmaxf(acc2[mf][nf][r] + bv[r], 0.f));
                *(s16x4*)(hb + (nf * 16 + lane16) * 72 + mf * 16 + lgrp * 4) = sv;
            }
        }

        f32x4 acc3[2];
        acc3[0] = (f32x4){0.f, 0.f, 0.f, 0.f};
        acc3[1] = (f32x4){0.f, 0.f, 0.f, 0.f};
        #pragma unroll
        for (int nf = 0; nf < 2; ++nf) {
            #pragma unroll
            for (int kb = 0; kb < 2; ++kb) {
                bf16x8 bh = *(const bf16x8*)(hb + (nf * 16 + lane16) * 72 + kb * 32 + lgrp * 8);
                acc3[nf] = __builtin_amdgcn_mfma_f32_16x16x32_bf16(a3[kb], bh, acc3[nf], 0, 0, 0);
            }
        }
        if (lgrp == 0) {
            #pragma unroll
            for (int nf = 0; nf < 2; ++nf)
                rawb[w][rep * 32 + nf * 16 + lane16] = acc3[nf] + b3v;
        }
    }

    // ---- wave-parallel volume rendering ----
    f32x4 rv = rawb[w][l];
    float dz = (farv - nearv) * (1.f / 63.f);
    float zl = nearv + (farv - nearv) * ((float)l / 63.0f);
    float delta = (l == 63) ? 1e10f : dz;
    float sigma = fmaxf(rv[3], 0.f);
    float alpha = 1.f - __expf(-sigma * delta);
    float la = __builtin_log2f(1.f - alpha + 1e-10f);

    float inc = la;
    #pragma unroll
    for (int off = 1; off < 64; off <<= 1) {
        float y = __shfl_up(inc, off);
        if (l >= off) inc += y;
    }
    float T = __builtin_exp2f(inc - la);
    float wt = alpha * T;

    float cr = wt / (1.f + __expf(-rv[0]));
    float cg = wt / (1.f + __expf(-rv[1]));
    float cb = wt / (1.f + __expf(-rv[2]));
    float cd = wt * zl;

    #pragma unroll
    for (int off = 32; off > 0; off >>= 1) {
        cr += __shfl_down(cr, off);
        cg += __shfl_down(cg, off);
        cb += __shfl_down(cb, off);
        cd += __shfl_down(cd, off);
    }
    if (l == 0) {
        out[pix]             = cr;
        out[4096 + pix]      = cg;
        out[2 * 4096 + pix]  = cb;
        out[12288 + pix]     = cd;
    }
}

extern "C" void kernel_launch(void* const* d_in, const int* in_sizes, int n_in,
                              void* d_out, int out_size, void* d_ws, size_t ws_size,
                              hipStream_t stream) {
    const float* images = (const float*)d_in[0];
    const float* rays   = (const float*)d_in[1];
    const float* w1 = (const float*)d_in[2];
    const float* b1 = (const float*)d_in[3];
    const float* w2 = (const float*)d_in[4];
    const float* b2 = (const float*)d_in[5];
    const float* w3 = (const float*)d_in[6];
    const float* b3 = (const float*)d_in[7];
    const float* mw1 = (const float*)d_in[8];
    const float* mb1 = (const float*)d_in[9];
    const float* mw2 = (const float*)d_in[10];
    const float* mb2 = (const float*)d_in[11];
    const float* mw3 = (const float*)d_in[12];
    const float* mb3 = (const float*)d_in[13];
    float* out = (float*)d_out;

    // workspace layout (bf16 region)
    __hip_bfloat16* A1c  = (__hip_bfloat16*)d_ws;              // 13107200 bf16
    __hip_bfloat16* WPK2 = A1c + 13107200;                     // 73728
    __hip_bfloat16* WPK1 = WPK2 + 73728;                       // 2048 (retired, kept for layout)
    __hip_bfloat16* VOLc = WPK1 + 2048;                        // 524288
    __hip_bfloat16* WPM1 = VOLc + 524288;                      // 2048
    __hip_bfloat16* WPM2 = WPM1 + 2048;                        // 4096
    __hip_bfloat16* WPM3 = WPM2 + 4096;                        // 1024
    __hip_bfloat16* A2c  = WPM3 + 1024;                        // 6553600
    __hip_bfloat16* XBc  = A2c + 6553600;                      // 131072
    __hip_bfloat16* WPK3 = XBc + 131072;                       // 589824

    conv1_pack<<<dim3(3524), dim3(256), 0, stream>>>(images, w1, b1, w2, w3, mw1, mb1, mw2, mw3,
                                                     A1c, WPK2, WPK3, WPM1, WPM2, WPM3);
    conv2_mfma<<<dim3(1792), dim3(128), 0, stream>>>(A1c, WPK2, b2, A2c);
    mean_kernel<<<dim3(256), dim3(64), 0, stream>>>(A2c, XBc);
    conv3_mfma<<<dim3(16, 32), dim3(128), 0, stream>>>(XBc, WPK3, b3, VOLc);
    mlp_render<<<dim3(1024), dim3(256), 0, stream>>>(VOLc, rays, WPM1, WPM2, WPM3, mb2, mb3, out);
}